// Round 9
// baseline (162.429 us; speedup 1.0000x reference)
//
#include <hip/hip_runtime.h>

// ---------------------------------------------------------------------------
// Round 9: micro set — b128 P reads in attn store, redundant lgkm drains
// removed, coalesced mhp epilogue, packed prep writes. Rest as round 8.
// B=2 Lq=1024 Lkv=2048 D=1024 H=16 dk=dv=64 SEG=256 nseg=8 L=8192
// d_out = [outputs (2*8192*1024) f32] ++ [attn_out (2*8192*16*256) f32]
// ---------------------------------------------------------------------------

#define B_ 2
#define LQ 1024
#define LKV 2048
#define D_ 1024
#define H_ 16
#define DK 64
#define SEGW 256
#define NSEG 8
#define LTOT 8192

typedef _Float16 f16;
typedef __attribute__((ext_vector_type(8))) _Float16 f16x8;
typedef __attribute__((ext_vector_type(4))) _Float16 f16x4;
typedef __attribute__((ext_vector_type(2))) _Float16 f16x2;
typedef __attribute__((ext_vector_type(4))) float f32x4;

#define MFMA_F16(a, b, c) __builtin_amdgcn_mfma_f32_16x16x32_f16((a), (b), (c), 0, 0, 0)

// ---------------- prep: all W transposes, 4 tiles per block -----------------
__global__ __launch_bounds__(256) void prep_kernel(
    const float* __restrict__ Wq, const float* __restrict__ Wk,
    const float* __restrict__ Wv, const float* __restrict__ Wh,
    f16* __restrict__ WqT, f16* __restrict__ WkT, f16* __restrict__ WvT,
    f16* __restrict__ WhT) {
  __shared__ float T[32][33];
  const int c = threadIdx.x & 31, r0 = threadIdx.x >> 5;
  const int c2 = (threadIdx.x & 15) * 2, r2 = threadIdx.x >> 4;
#pragma unroll 1
  for (int t = 0; t < 4; ++t) {
    const int gidx = blockIdx.x * 4 + t;
    const float* src;
    f16* dst;
    int N, D2, d0, n0;
    size_t soff = 0, doff = 0;
    if (gidx < 2048) {
      int z = gidx >> 6, inner = gidx & 63;
      int h = z & 15;
      src = (z < 16) ? Wq : Wk;
      dst = (z < 16) ? WqT : WkT;
      soff = (size_t)h * (1024 * 64);
      doff = (size_t)h * (64 * 1024);
      N = 64; D2 = 1024;
      d0 = (inner & 31) * 32;
      n0 = (inner >> 5) * 32;
    } else if (gidx < 2112) {
      int i = gidx - 2048;
      src = Wv; dst = WvT; N = 64; D2 = 1024;
      d0 = (i & 31) * 32;
      n0 = (i >> 5) * 32;
    } else {
      int i = gidx - 2112;
      src = Wh; dst = WhT; N = 1024; D2 = 64;
      d0 = (i & 1) * 32;
      n0 = (i >> 1) * 32;
    }
#pragma unroll
    for (int i = 0; i < 4; ++i) {
      int r = r0 + i * 8;
      T[r][c] = src[soff + (size_t)(d0 + r) * N + n0 + c];
    }
    __syncthreads();
#pragma unroll
    for (int i = 0; i < 2; ++i) {
      int rr = r2 + i * 16;  // n-dim
      f16x2 v2;
      v2[0] = (f16)T[c2][rr];
      v2[1] = (f16)T[c2 + 1][rr];
      *(f16x2*)(dst + doff + (size_t)(n0 + rr) * D2 + d0 + c2) = v2;
    }
    __syncthreads();
  }
}

// ---------------- projection bodies (pipelined, repacked epilogue) ----------
__device__ __forceinline__ void proj_body(
    const float* __restrict__ A, const f16* __restrict__ WT,
    const float* __restrict__ bias, f16* __restrict__ C, int Mb, int bshift,
    int m0, int c0, char* smem) {
  f16(*Ah)[40] = (f16(*)[40])smem;
  f16(*Bh)[40] = (f16(*)[40])(smem + 20480);
  const int tid = threadIdx.x, lane = tid & 63, w = tid >> 6;
  const int wr = w >> 1, wc = w & 1;
  const int l15 = lane & 15, l4 = lane >> 4;
  const int f4 = tid & 7, row0 = tid >> 3;  // A loader: 4 rows, 16B each
  const int u = tid & 3, cb = tid >> 2;     // B loader: 2 rows, 16B each

  f32x4 acc[4][4];
#pragma unroll
  for (int i = 0; i < 4; ++i)
#pragma unroll
    for (int j = 0; j < 4; ++j) acc[i][j] = (f32x4)0.f;

  float4 aR[4];
  f16x8 bR[2];

#define PLOAD(k0)                                                              \
  {                                                                            \
    _Pragma("unroll") for (int p = 0; p < 4; ++p) aR[p] =                      \
        *(const float4*)(A + (size_t)(m0 + row0 + p * 32) * 1024 + (k0) +      \
                         f4 * 4);                                              \
    _Pragma("unroll") for (int p = 0; p < 2; ++p) bR[p] =                      \
        *(const f16x8*)(WT + (size_t)(c0 + cb + p * 64) * 1024 + (k0) +        \
                        u * 8);                                                \
  }
#define PSTORE(bi)                                                             \
  {                                                                            \
    _Pragma("unroll") for (int p = 0; p < 4; ++p) {                            \
      f16x4 h4;                                                                \
      h4[0] = (f16)aR[p].x; h4[1] = (f16)aR[p].y;                              \
      h4[2] = (f16)aR[p].z; h4[3] = (f16)aR[p].w;                              \
      *(f16x4*)&Ah[(bi)*128 + row0 + p * 32][f4 * 4] = h4;                     \
    }                                                                          \
    _Pragma("unroll") for (int p = 0; p < 2; ++p)                              \
        *(f16x8*)&Bh[(bi)*128 + cb + p * 64][u * 8] = bR[p];                   \
  }

  PLOAD(0);
  PSTORE(0);
  __syncthreads();

#pragma unroll 2
  for (int k = 0; k < 32; ++k) {
    if (k + 1 < 32) PLOAD((k + 1) * 32);  // in flight during compute
    const int cbuf = (k & 1) * 128;
    f16x8 ah[4], bh[4];
#pragma unroll
    for (int i = 0; i < 4; ++i) {
      ah[i] = *(const f16x8*)&Ah[cbuf + wr * 64 + i * 16 + l15][l4 * 8];
      bh[i] = *(const f16x8*)&Bh[cbuf + wc * 64 + i * 16 + l15][l4 * 8];
    }
#pragma unroll
    for (int i = 0; i < 4; ++i)
#pragma unroll
      for (int j = 0; j < 4; ++j) acc[i][j] = MFMA_F16(ah[i], bh[j], acc[i][j]);
    if (k + 1 < 32) PSTORE((k + 1) & 1);
    __syncthreads();
  }
#undef PLOAD
#undef PSTORE

  // ---- coalesced C store via LDS repack ----
  f16(*Cst)[136] = (f16(*)[136])smem;  // 128x136 f16 = 34816 B
#pragma unroll
  for (int j = 0; j < 4; ++j) {
    int cl = wc * 64 + j * 16 + l15;
    float bs = bias[c0 + cl];
#pragma unroll
    for (int i = 0; i < 4; ++i)
#pragma unroll
      for (int r = 0; r < 4; ++r)
        Cst[wr * 64 + i * 16 + l4 * 4 + r][cl] = (f16)(acc[i][j][r] + bs);
  }
  __syncthreads();
#pragma unroll
  for (int p = 0; p < 8; ++p) {
    int row = p * 16 + (tid >> 4);
    int col = (tid & 15) * 8;
    f16x8 vv = *(const f16x8*)&Cst[row][col];
    int m = m0 + row, c = c0 + col;
    int bb = m >> bshift, ml = m - (bb << bshift);
    int hidx = c >> 6, dk = c & 63;
    *(f16x8*)(C + ((size_t)(bb * 16 + hidx) * Mb + ml) * 64 + dk) = vv;
  }
}

__device__ __forceinline__ void vproj_body(
    const float* __restrict__ v, const f16* __restrict__ WvT,
    const float* __restrict__ bv, f16* __restrict__ vpTg, int m0, char* smem) {
  f16(*Av)[40] = (f16(*)[40])smem;
  f16(*Bv)[40] = (f16(*)[40])(smem + 10240);
  const int tid = threadIdx.x, lane = tid & 63, w = tid >> 6;
  const int l15 = lane & 15, l4 = lane >> 4;
  const int f4 = tid & 7, row0 = tid >> 3;  // A loader: 2 rows
  const int u = tid & 3, cb = tid >> 2;     // B loader: 1 row

  f32x4 acc[4];
#pragma unroll
  for (int j = 0; j < 4; ++j) acc[j] = (f32x4)0.f;

  float4 aR[2];
  f16x8 bR;

#define VLOAD(k0)                                                              \
  {                                                                            \
    _Pragma("unroll") for (int p = 0; p < 2; ++p) aR[p] =                      \
        *(const float4*)(v + (size_t)(m0 + row0 + p * 32) * 1024 + (k0) +      \
                         f4 * 4);                                              \
    bR = *(const f16x8*)(WvT + (size_t)cb * 1024 + (k0) + u * 8);              \
  }
#define VSTORE(bi)                                                             \
  {                                                                            \
    _Pragma("unroll") for (int p = 0; p < 2; ++p) {                            \
      f16x4 h4;                                                                \
      h4[0] = (f16)aR[p].x; h4[1] = (f16)aR[p].y;                              \
      h4[2] = (f16)aR[p].z; h4[3] = (f16)aR[p].w;                              \
      *(f16x4*)&Av[(bi)*64 + row0 + p * 32][f4 * 4] = h4;                      \
    }                                                                          \
    *(f16x8*)&Bv[(bi)*64 + cb][u * 8] = bR;                                    \
  }

  VLOAD(0);
  VSTORE(0);
  __syncthreads();

#pragma unroll 2
  for (int k = 0; k < 32; ++k) {
    if (k + 1 < 32) VLOAD((k + 1) * 32);
    const int cbuf = (k & 1) * 64;
    f16x8 a8 = *(const f16x8*)&Av[cbuf + w * 16 + l15][l4 * 8];
#pragma unroll
    for (int cf = 0; cf < 4; ++cf) {
      f16x8 b8 = *(const f16x8*)&Bv[cbuf + cf * 16 + l15][l4 * 8];
      acc[cf] = MFMA_F16(a8, b8, acc[cf]);
    }
    if (k + 1 < 32) VSTORE((k + 1) & 1);
    __syncthreads();
  }
#undef VLOAD
#undef VSTORE

  // ---- coalesced vpTg store via LDS repack ----
  f16(*Vst)[72] = (f16(*)[72])smem;  // 64x72 f16 = 9216 B
#pragma unroll
  for (int cf = 0; cf < 4; ++cf) {
    float bvv = bv[cf * 16 + l15];
#pragma unroll
    for (int r = 0; r < 4; ++r)
      Vst[cf * 16 + l15][w * 16 + l4 * 4 + r] = (f16)(acc[cf][r] + bvv);
  }
  __syncthreads();
  const int b = m0 >> 11, rest = m0 & 2047, n = rest >> 8, si0 = rest & 255;
#pragma unroll
  for (int p = 0; p < 2; ++p) {
    int row = p * 32 + (tid >> 3);
    int col = (tid & 7) * 8;
    f16x8 vv = *(const f16x8*)&Vst[row][col];
    *(f16x8*)(vpTg + ((size_t)((b * 8 + n) * 64 + row)) * 256 + si0 + col) = vv;
  }
}

__global__ __launch_bounds__(256) void proj_all_kernel(
    const float* __restrict__ q, const float* __restrict__ k,
    const float* __restrict__ v, const f16* __restrict__ WqT,
    const f16* __restrict__ WkT, const f16* __restrict__ WvT,
    const float* __restrict__ bq, const float* __restrict__ bk,
    const float* __restrict__ bv, f16* __restrict__ qs, f16* __restrict__ kp,
    f16* __restrict__ vpTg) {
  __shared__ __align__(16) char smem[40960];
  const int bid = blockIdx.x;
  if (bid < 128) {
    proj_body(q, WqT, bq, qs, 1024, 10, (bid & 15) * 128, (bid >> 4) * 128, smem);
  } else if (bid < 384) {
    int i = bid - 128;
    proj_body(k, WkT, bk, kp, 2048, 11, (i & 31) * 128, (i >> 5) * 128, smem);
  } else {
    vproj_body(v, WvT, bv, vpTg, (bid - 384) * 64, smem);
  }
}

// ---------------- fused attention -----------------------------------------
// grid 512: (pair 16) x (qt 16) x (head-half 2), XCD-swizzled.
__global__ __launch_bounds__(256, 2) void fused_attn_kernel(
    const f16* __restrict__ qs, const f16* __restrict__ kp,
    const f16* __restrict__ vpTg, float* __restrict__ attn_out,
    f16* __restrict__ mhp) {
  __shared__ __align__(16) char Kbuf[2][32768];

  const int bid = blockIdx.x;
  const int xcd = bid & 7, sub = bid >> 3;
  const int gg = xcd * 4 + (sub >> 4);  // 0..31
  const int qt = sub & 15;
  const int pair = gg & 15, hgIdx = gg >> 4;
  const int b = pair >> 3, n = pair & 7;
  const int q0 = qt * 64;

  const int tid = threadIdx.x, lane = tid & 63, w = tid >> 6;
  const int l15 = lane & 15, l4 = lane >> 4;

  // per-lane inverse-swizzled source offset (rule #21)
  const int laneoff =
      (lane >> 3) * 128 + (((lane & 7) * 16) ^ ((lane >> 3) << 4));

  // V fragments (wave's dv quarter), reused across all heads  [8 x b128]
  f16x8 vfrag[8];
  {
    const f16* vb = vpTg + ((size_t)(pair * 64 + w * 16 + l15)) * 256 + l4 * 8;
#pragma unroll
    for (int kc = 0; kc < 8; ++kc) vfrag[kc] = *(const f16x8*)(vb + kc * 32);
  }

#define STAGE_K(bufIdx, h)                                                      \
  {                                                                             \
    const char* src_ = (const char*)kp +                                        \
        ((size_t)((b * 16 + (h)) * 2048 + n * 256)) * 128;                      \
    char* lds_ = &Kbuf[bufIdx][0];                                              \
    _Pragma("unroll")                                                           \
    for (int j_ = 0; j_ < 8; ++j_) {                                            \
      int ch_ = w * 8 + j_;                                                     \
      __builtin_amdgcn_global_load_lds(                                         \
          (const __attribute__((address_space(1))) unsigned int*)(src_ +        \
              ch_ * 1024 + laneoff),                                            \
          (__attribute__((address_space(3))) unsigned int*)(lds_ + ch_ * 1024), \
          16, 0, 0);                                                            \
    }                                                                           \
  }

#define LOAD_Q(h, a0, a1)                                                       \
  {                                                                             \
    const f16* qp_ = qs +                                                       \
        ((size_t)((b * 16 + (h)) * 1024 + q0 + w * 16 + l15)) * 64 + l4 * 8;    \
    a0 = *(const f16x8*)qp_;                                                    \
    a1 = *(const f16x8*)(qp_ + 32);                                             \
  }

  f16x8 qa0, qa1, qn0, qn1;
  STAGE_K(0, hgIdx * 8);            // 8 loads
  LOAD_Q(hgIdx * 8, qa0, qa1);      // 2 loads
  qn0 = qa0; qn1 = qa1;

  f32x4 accO[4];
#pragma unroll
  for (int i = 0; i < 4; ++i) accO[i] = (f32x4)0.f;

  // outstanding: vfrag(8) + stage(8) + Q(2); vmcnt(2) => vfrag+stage retired
  asm volatile("s_waitcnt vmcnt(2)" ::: "memory");
  __builtin_amdgcn_s_barrier();

  const int ql = w * 16 + l15;        // this lane's q row within the 64-tile
  const int swq = (ql & 7) << 4;      // P swizzle for this lane's row

#pragma unroll 1
  for (int hh = 0; hh < 8; ++hh) {
    const int h = hgIdx * 8 + hh;
    const int cur = hh & 1;
    if (hh < 7) {
      STAGE_K(cur ^ 1, h + 1);      // 8 loads (oldest of this iteration)
      LOAD_Q(h + 1, qn0, qn1);      // 2 loads
    }

    // ---- QK^T (swapped): accS[sf][r] = S[q=ql][s=sf*16+l4*4+r] ----
    f32x4 accS[16];
#pragma unroll
    for (int sf = 0; sf < 16; ++sf) accS[sf] = (f32x4)0.f;
    const char* Kc = &Kbuf[cur][0];
    {
      const int sw = (l15 & 7) << 4;
      __builtin_amdgcn_s_setprio(1);
#pragma unroll
      for (int sf = 0; sf < 16; ++sf) {
        const int rowb = (sf * 16 + l15) * 128;
        f16x8 b0 = *(const f16x8*)(Kc + rowb + ((l4 * 16) ^ sw));
        f16x8 b1 = *(const f16x8*)(Kc + rowb + ((64 + l4 * 16) ^ sw));
        accS[sf] = MFMA_F16(b0, qa0, accS[sf]);
        accS[sf] = MFMA_F16(b1, qa1, accS[sf]);
      }
      __builtin_amdgcn_s_setprio(0);
    }

    // ---- softmax: lane-local row, 2+2 shfl across l4 groups ----
    float mx = -3.0e38f;
    if (q0 < SEGW) {  // uniform: only qt<4 ever masks
      const int qg = q0 + ql;
#pragma unroll
      for (int sf = 0; sf < 16; ++sf)
#pragma unroll
        for (int r = 0; r < 4; ++r) {
          int s = sf * 16 + l4 * 4 + r;
          float vv = accS[sf][r] * 0.125f;
          if (s > qg) vv = -3.0e38f;
          accS[sf][r] = vv;
          mx = fmaxf(mx, vv);
        }
    } else {
#pragma unroll
      for (int sf = 0; sf < 16; ++sf)
#pragma unroll
        for (int r = 0; r < 4; ++r) {
          float vv = accS[sf][r] * 0.125f;
          accS[sf][r] = vv;
          mx = fmaxf(mx, vv);
        }
    }
    mx = fmaxf(mx, __shfl_xor(mx, 16));
    mx = fmaxf(mx, __shfl_xor(mx, 32));
    float sum = 0.f;
#pragma unroll
    for (int sf = 0; sf < 16; ++sf)
#pragma unroll
      for (int r = 0; r < 4; ++r) {
        float e = __expf(accS[sf][r] - mx);
        accS[sf][r] = e;
        sum += e;
      }
    sum += __shfl_xor(sum, 16);
    sum += __shfl_xor(sum, 32);
    const float inv = 1.0f / sum;

    // all waves done reading K[cur] (QK ds_reads consumed by MFMAs) ->
    // safe to overlay P after barrier; no explicit lgkm drain needed.
    __builtin_amdgcn_s_barrier();

    // ---- write P (f16, swizzled): 16 x ds_write_b64, 4 consecutive s ----
    char* Pc = &Kbuf[cur][0];
#pragma unroll
    for (int sf = 0; sf < 16; ++sf) {
      f16x4 p4;
      p4[0] = (f16)(accS[sf][0] * inv);
      p4[1] = (f16)(accS[sf][1] * inv);
      p4[2] = (f16)(accS[sf][2] * inv);
      p4[3] = (f16)(accS[sf][3] * inv);
      *(f16x4*)(Pc + ql * 512 + ((sf * 32 + l4 * 8) ^ swq)) = p4;
    }
    asm volatile("s_waitcnt lgkmcnt(0)" ::: "memory");
    __builtin_amdgcn_s_barrier();

    // ---- PV first: MFMAs enter the pipe; stores issue under them ----
    __builtin_amdgcn_s_setprio(1);
#pragma unroll
    for (int kc = 0; kc < 8; ++kc) {
#pragma unroll
      for (int qb = 0; qb < 4; ++qb) {
        const int qr = qb * 16 + l15;
        f16x8 pa = *(const f16x8*)(Pc + qr * 512 +
                                   ((kc * 64 + l4 * 16) ^ ((qr & 7) << 4)));
        accO[qb] = MFMA_F16(pa, vfrag[kc], accO[qb]);
      }
    }
    __builtin_amdgcn_s_setprio(0);

    // ---- attn_out: b128 P reads, 2 NT f32x4 stores each (16 stores/lane) ----
    {
      const size_t base0 =
          (((size_t)b * LTOT + (size_t)n * LQ + q0) * H_ + h) * SEGW;
      const int l32 = lane & 31;
#pragma unroll
      for (int it = 0; it < 8; ++it) {
        const int qr = w * 16 + it * 2 + (lane >> 5);
        f16x8 p8 =
            *(const f16x8*)(Pc + qr * 512 + ((l32 * 16) ^ ((qr & 7) << 4)));
        f32x4 f0, f1;
        f0[0] = (float)p8[0]; f0[1] = (float)p8[1];
        f0[2] = (float)p8[2]; f0[3] = (float)p8[3];
        f1[0] = (float)p8[4]; f1[1] = (float)p8[5];
        f1[2] = (float)p8[6]; f1[3] = (float)p8[7];
        float* op = attn_out + base0 + (size_t)qr * (H_ * SEGW) + l32 * 8;
        __builtin_nontemporal_store(f0, (f32x4*)op);
        __builtin_nontemporal_store(f1, (f32x4*)(op + 4));
      }
    }

    qa0 = qn0; qa1 = qn1;
    // vmcnt(16): drains prev stores + stage + Q; leaves this head's 16 NT
    // stores draining under head h+1's compute. LDS reads already consumed.
    asm volatile("s_waitcnt vmcnt(16)" ::: "memory");
    __builtin_amdgcn_s_barrier();
  }

  // ---- epilogue: coalesced mhp via LDS repack (Kbuf[0] dead) ----
  {
    f16(*Lst)[64] = (f16(*)[64]) & Kbuf[0][0];  // 64 q x 64 dv = 8 KB
    const float s16 = 1.0f / 16.0f;
#pragma unroll
    for (int qb = 0; qb < 4; ++qb)
#pragma unroll
      for (int r = 0; r < 4; ++r)
        Lst[qb * 16 + l4 * 4 + r][w * 16 + l15] = (f16)(accO[qb][r] * s16);
    __syncthreads();
    f16* mp = mhp + ((size_t)hgIdx * 16384 + (size_t)pair * 1024 + q0) * 64;
    const int row = tid >> 2, col = (tid & 3) * 16;
    f16x8 v0 = *(const f16x8*)&Lst[row][col];
    f16x8 v1 = *(const f16x8*)&Lst[row][col + 8];
    *(f16x8*)(mp + (size_t)row * 64 + col) = v0;
    *(f16x8*)(mp + (size_t)row * 64 + col + 8) = v1;
  }
#undef STAGE_K
#undef LOAD_Q
}

// ---------------- final: outputs = (mhp0+mhp1)[16384,64] @ Wh[64,1024] -----
__global__ __launch_bounds__(256) void final_f16_kernel(
    const f16* __restrict__ mhp, const f16* __restrict__ WhT,
    float* __restrict__ outputs) {
  __shared__ __align__(16) char smemF[33792];
  f16(*Af)[72] = (f16(*)[72])smemF;
  f16(*Bf)[72] = (f16(*)[72])(smemF + 9216);
  const int m0 = blockIdx.x * 64, c0 = blockIdx.y * 128;
  const int tid = threadIdx.x, lane = tid & 63, w = tid >> 6;
  const int l15 = lane & 15, l4 = lane >> 4;
  {
    int u = tid & 7, row0 = tid >> 3;
#pragma unroll
    for (int p = 0; p < 2; ++p) {
      int r = row0 + p * 32;
      size_t mi = (size_t)(m0 + r) * 64 + u * 8;
      f16x8 a0 = *(const f16x8*)(mhp + mi);
      f16x8 a1 = *(const f16x8*)(mhp + (size_t)16384 * 64 + mi);
      *(f16x8*)&Af[r][u * 8] = a0 + a1;
    }
    int cb = tid >> 3;
#pragma unroll
    for (int p = 0; p < 4; ++p) {
      int c = cb + p * 32;
      *(f16x8*)&Bf[c][u * 8] = *(const f16x8*)(WhT + (size_t)(c0 + c) * 64 + u * 8);
    }
  }
  __syncthreads();

  f32x4 acc[8];
#pragma unroll
  for (int cf = 0; cf < 8; ++cf) acc[cf] = (f32x4)0.f;
#pragma unroll
  for (int kc = 0; kc < 2; ++kc) {
    f16x8 a8 = *(const f16x8*)&Af[w * 16 + l15][kc * 32 + l4 * 8];
#pragma unroll
    for (int cf = 0; cf < 8; ++cf) {
      f16x8 b8 = *(const f16x8*)&Bf[cf * 16 + l15][kc * 32 + l4 * 8];
      acc[cf] = MFMA_F16(a8, b8, acc[cf]);
    }
  }
  __syncthreads();  // Af/Bf reads done -> overlay staging

  // ---- coalesced outputs store via LDS repack ----
  float(*Cst)[132] = (float(*)[132])smemF;
#pragma unroll
  for (int cf = 0; cf < 8; ++cf)
#pragma unroll
    for (int r = 0; r < 4; ++r)
      Cst[w * 16 + l4 * 4 + r][cf * 16 + l15] = acc[cf][r];
  __syncthreads();
#pragma unroll
  for (int p = 0; p < 8; ++p) {
    int row = p * 8 + (tid >> 5);
    int col = (tid & 31) * 4;
    f32x4 vv = *(const f32x4*)&Cst[row][col];
    __builtin_nontemporal_store(
        vv, (f32x4*)(outputs + (size_t)(m0 + row) * 1024 + c0 + col));
  }
}

// ---------------------------------------------------------------------------
extern "C" void kernel_launch(void* const* d_in, const int* in_sizes, int n_in,
                              void* d_out, int out_size, void* d_ws,
                              size_t ws_size, hipStream_t stream) {
  const float* q  = (const float*)d_in[0];
  const float* k  = (const float*)d_in[1];
  const float* v  = (const float*)d_in[2];
  const float* Wq = (const float*)d_in[3];
  const float* bq = (const float*)d_in[4];
  const float* Wk = (const float*)d_in[5];
  const float* bk = (const float*)d_in[6];
  const float* Wv = (const float*)d_in[7];
  const float* bv = (const float*)d_in[8];
  const float* Wh = (const float*)d_in[9];

  float* outputs  = (float*)d_out;
  float* attn_out = (float*)d_out + (size_t)B_ * LTOT * D_;

  char* ws = (char*)d_ws;
  f16* WqT  = (f16*)(ws + 0);                       // 2MB
  f16* WkT  = (f16*)(ws + (2u << 20));              // 2MB
  f16* WvT  = (f16*)(ws + (4u << 20));              // 128KB
  f16* WhT  = (f16*)(ws + (4u << 20) + 131072);     // 128KB
  f16* qs   = (f16*)(ws + (4u << 20) + 262144);     // 4MB
  f16* kp   = (f16*)((char*)qs + (4u << 20));       // 8MB
  f16* vpTg = (f16*)((char*)kp + (8u << 20));       // 512KB
  f16* mhp  = (f16*)((char*)vpTg + (1u << 19));     // 4MB (2 partials)

  prep_kernel<<<dim3(544), 256, 0, stream>>>(Wq, Wk, Wv, Wh, WqT, WkT, WvT, WhT);
  proj_all_kernel<<<dim3(448), 256, 0, stream>>>(q, k, v, WqT, WkT, WvT, bq, bk,
                                                 bv, qs, kp, vpTg);
  fused_attn_kernel<<<dim3(512), 256, 0, stream>>>(qs, kp, vpTg, attn_out, mhp);
  final_f16_kernel<<<dim3(256, 8), 256, 0, stream>>>(mhp, WhT, outputs);
}

// Round 10
// 114.742 us; speedup vs baseline: 1.4156x; 1.4156x over previous
//
#include <hip/hip_runtime.h>

// ---------------------------------------------------------------------------
// Round 10: revert round-9's attn-store pattern (it halved NT-store segment
// efficiency on the 268MB write path). Round 8 store loop + lgkm drains
// restored; keep prep f16x2 packing and coalesced mhp epilogue.
// B=2 Lq=1024 Lkv=2048 D=1024 H=16 dk=dv=64 SEG=256 nseg=8 L=8192
// d_out = [outputs (2*8192*1024) f32] ++ [attn_out (2*8192*16*256) f32]
// ---------------------------------------------------------------------------

#define B_ 2
#define LQ 1024
#define LKV 2048
#define D_ 1024
#define H_ 16
#define DK 64
#define SEGW 256
#define NSEG 8
#define LTOT 8192

typedef _Float16 f16;
typedef __attribute__((ext_vector_type(8))) _Float16 f16x8;
typedef __attribute__((ext_vector_type(4))) _Float16 f16x4;
typedef __attribute__((ext_vector_type(2))) _Float16 f16x2;
typedef __attribute__((ext_vector_type(4))) float f32x4;

#define MFMA_F16(a, b, c) __builtin_amdgcn_mfma_f32_16x16x32_f16((a), (b), (c), 0, 0, 0)

// ---------------- prep: all W transposes, 4 tiles per block -----------------
__global__ __launch_bounds__(256) void prep_kernel(
    const float* __restrict__ Wq, const float* __restrict__ Wk,
    const float* __restrict__ Wv, const float* __restrict__ Wh,
    f16* __restrict__ WqT, f16* __restrict__ WkT, f16* __restrict__ WvT,
    f16* __restrict__ WhT) {
  __shared__ float T[32][33];
  const int c = threadIdx.x & 31, r0 = threadIdx.x >> 5;
  const int c2 = (threadIdx.x & 15) * 2, r2 = threadIdx.x >> 4;
#pragma unroll 1
  for (int t = 0; t < 4; ++t) {
    const int gidx = blockIdx.x * 4 + t;
    const float* src;
    f16* dst;
    int N, D2, d0, n0;
    size_t soff = 0, doff = 0;
    if (gidx < 2048) {
      int z = gidx >> 6, inner = gidx & 63;
      int h = z & 15;
      src = (z < 16) ? Wq : Wk;
      dst = (z < 16) ? WqT : WkT;
      soff = (size_t)h * (1024 * 64);
      doff = (size_t)h * (64 * 1024);
      N = 64; D2 = 1024;
      d0 = (inner & 31) * 32;
      n0 = (inner >> 5) * 32;
    } else if (gidx < 2112) {
      int i = gidx - 2048;
      src = Wv; dst = WvT; N = 64; D2 = 1024;
      d0 = (i & 31) * 32;
      n0 = (i >> 5) * 32;
    } else {
      int i = gidx - 2112;
      src = Wh; dst = WhT; N = 1024; D2 = 64;
      d0 = (i & 1) * 32;
      n0 = (i >> 1) * 32;
    }
#pragma unroll
    for (int i = 0; i < 4; ++i) {
      int r = r0 + i * 8;
      T[r][c] = src[soff + (size_t)(d0 + r) * N + n0 + c];
    }
    __syncthreads();
#pragma unroll
    for (int i = 0; i < 2; ++i) {
      int rr = r2 + i * 16;  // n-dim
      f16x2 v2;
      v2[0] = (f16)T[c2][rr];
      v2[1] = (f16)T[c2 + 1][rr];
      *(f16x2*)(dst + doff + (size_t)(n0 + rr) * D2 + d0 + c2) = v2;
    }
    __syncthreads();
  }
}

// ---------------- projection bodies (pipelined, repacked epilogue) ----------
__device__ __forceinline__ void proj_body(
    const float* __restrict__ A, const f16* __restrict__ WT,
    const float* __restrict__ bias, f16* __restrict__ C, int Mb, int bshift,
    int m0, int c0, char* smem) {
  f16(*Ah)[40] = (f16(*)[40])smem;
  f16(*Bh)[40] = (f16(*)[40])(smem + 20480);
  const int tid = threadIdx.x, lane = tid & 63, w = tid >> 6;
  const int wr = w >> 1, wc = w & 1;
  const int l15 = lane & 15, l4 = lane >> 4;
  const int f4 = tid & 7, row0 = tid >> 3;  // A loader: 4 rows, 16B each
  const int u = tid & 3, cb = tid >> 2;     // B loader: 2 rows, 16B each

  f32x4 acc[4][4];
#pragma unroll
  for (int i = 0; i < 4; ++i)
#pragma unroll
    for (int j = 0; j < 4; ++j) acc[i][j] = (f32x4)0.f;

  float4 aR[4];
  f16x8 bR[2];

#define PLOAD(k0)                                                              \
  {                                                                            \
    _Pragma("unroll") for (int p = 0; p < 4; ++p) aR[p] =                      \
        *(const float4*)(A + (size_t)(m0 + row0 + p * 32) * 1024 + (k0) +      \
                         f4 * 4);                                              \
    _Pragma("unroll") for (int p = 0; p < 2; ++p) bR[p] =                      \
        *(const f16x8*)(WT + (size_t)(c0 + cb + p * 64) * 1024 + (k0) +        \
                        u * 8);                                                \
  }
#define PSTORE(bi)                                                             \
  {                                                                            \
    _Pragma("unroll") for (int p = 0; p < 4; ++p) {                            \
      f16x4 h4;                                                                \
      h4[0] = (f16)aR[p].x; h4[1] = (f16)aR[p].y;                              \
      h4[2] = (f16)aR[p].z; h4[3] = (f16)aR[p].w;                              \
      *(f16x4*)&Ah[(bi)*128 + row0 + p * 32][f4 * 4] = h4;                     \
    }                                                                          \
    _Pragma("unroll") for (int p = 0; p < 2; ++p)                              \
        *(f16x8*)&Bh[(bi)*128 + cb + p * 64][u * 8] = bR[p];                   \
  }

  PLOAD(0);
  PSTORE(0);
  __syncthreads();

#pragma unroll 2
  for (int k = 0; k < 32; ++k) {
    if (k + 1 < 32) PLOAD((k + 1) * 32);  // in flight during compute
    const int cbuf = (k & 1) * 128;
    f16x8 ah[4], bh[4];
#pragma unroll
    for (int i = 0; i < 4; ++i) {
      ah[i] = *(const f16x8*)&Ah[cbuf + wr * 64 + i * 16 + l15][l4 * 8];
      bh[i] = *(const f16x8*)&Bh[cbuf + wc * 64 + i * 16 + l15][l4 * 8];
    }
#pragma unroll
    for (int i = 0; i < 4; ++i)
#pragma unroll
      for (int j = 0; j < 4; ++j) acc[i][j] = MFMA_F16(ah[i], bh[j], acc[i][j]);
    if (k + 1 < 32) PSTORE((k + 1) & 1);
    __syncthreads();
  }
#undef PLOAD
#undef PSTORE

  // ---- coalesced C store via LDS repack ----
  f16(*Cst)[136] = (f16(*)[136])smem;  // 128x136 f16 = 34816 B
#pragma unroll
  for (int j = 0; j < 4; ++j) {
    int cl = wc * 64 + j * 16 + l15;
    float bs = bias[c0 + cl];
#pragma unroll
    for (int i = 0; i < 4; ++i)
#pragma unroll
      for (int r = 0; r < 4; ++r)
        Cst[wr * 64 + i * 16 + l4 * 4 + r][cl] = (f16)(acc[i][j][r] + bs);
  }
  __syncthreads();
#pragma unroll
  for (int p = 0; p < 8; ++p) {
    int row = p * 16 + (tid >> 4);
    int col = (tid & 15) * 8;
    f16x8 vv = *(const f16x8*)&Cst[row][col];
    int m = m0 + row, c = c0 + col;
    int bb = m >> bshift, ml = m - (bb << bshift);
    int hidx = c >> 6, dk = c & 63;
    *(f16x8*)(C + ((size_t)(bb * 16 + hidx) * Mb + ml) * 64 + dk) = vv;
  }
}

__device__ __forceinline__ void vproj_body(
    const float* __restrict__ v, const f16* __restrict__ WvT,
    const float* __restrict__ bv, f16* __restrict__ vpTg, int m0, char* smem) {
  f16(*Av)[40] = (f16(*)[40])smem;
  f16(*Bv)[40] = (f16(*)[40])(smem + 10240);
  const int tid = threadIdx.x, lane = tid & 63, w = tid >> 6;
  const int l15 = lane & 15, l4 = lane >> 4;
  const int f4 = tid & 7, row0 = tid >> 3;  // A loader: 2 rows
  const int u = tid & 3, cb = tid >> 2;     // B loader: 1 row

  f32x4 acc[4];
#pragma unroll
  for (int j = 0; j < 4; ++j) acc[j] = (f32x4)0.f;

  float4 aR[2];
  f16x8 bR;

#define VLOAD(k0)                                                              \
  {                                                                            \
    _Pragma("unroll") for (int p = 0; p < 2; ++p) aR[p] =                      \
        *(const float4*)(v + (size_t)(m0 + row0 + p * 32) * 1024 + (k0) +      \
                         f4 * 4);                                              \
    bR = *(const f16x8*)(WvT + (size_t)cb * 1024 + (k0) + u * 8);              \
  }
#define VSTORE(bi)                                                             \
  {                                                                            \
    _Pragma("unroll") for (int p = 0; p < 2; ++p) {                            \
      f16x4 h4;                                                                \
      h4[0] = (f16)aR[p].x; h4[1] = (f16)aR[p].y;                              \
      h4[2] = (f16)aR[p].z; h4[3] = (f16)aR[p].w;                              \
      *(f16x4*)&Av[(bi)*64 + row0 + p * 32][f4 * 4] = h4;                      \
    }                                                                          \
    *(f16x8*)&Bv[(bi)*64 + cb][u * 8] = bR;                                    \
  }

  VLOAD(0);
  VSTORE(0);
  __syncthreads();

#pragma unroll 2
  for (int k = 0; k < 32; ++k) {
    if (k + 1 < 32) VLOAD((k + 1) * 32);
    const int cbuf = (k & 1) * 64;
    f16x8 a8 = *(const f16x8*)&Av[cbuf + w * 16 + l15][l4 * 8];
#pragma unroll
    for (int cf = 0; cf < 4; ++cf) {
      f16x8 b8 = *(const f16x8*)&Bv[cbuf + cf * 16 + l15][l4 * 8];
      acc[cf] = MFMA_F16(a8, b8, acc[cf]);
    }
    if (k + 1 < 32) VSTORE((k + 1) & 1);
    __syncthreads();
  }
#undef VLOAD
#undef VSTORE

  // ---- coalesced vpTg store via LDS repack ----
  f16(*Vst)[72] = (f16(*)[72])smem;  // 64x72 f16 = 9216 B
#pragma unroll
  for (int cf = 0; cf < 4; ++cf) {
    float bvv = bv[cf * 16 + l15];
#pragma unroll
    for (int r = 0; r < 4; ++r)
      Vst[cf * 16 + l15][w * 16 + l4 * 4 + r] = (f16)(acc[cf][r] + bvv);
  }
  __syncthreads();
  const int b = m0 >> 11, rest = m0 & 2047, n = rest >> 8, si0 = rest & 255;
#pragma unroll
  for (int p = 0; p < 2; ++p) {
    int row = p * 32 + (tid >> 3);
    int col = (tid & 7) * 8;
    f16x8 vv = *(const f16x8*)&Vst[row][col];
    *(f16x8*)(vpTg + ((size_t)((b * 8 + n) * 64 + row)) * 256 + si0 + col) = vv;
  }
}

__global__ __launch_bounds__(256) void proj_all_kernel(
    const float* __restrict__ q, const float* __restrict__ k,
    const float* __restrict__ v, const f16* __restrict__ WqT,
    const f16* __restrict__ WkT, const f16* __restrict__ WvT,
    const float* __restrict__ bq, const float* __restrict__ bk,
    const float* __restrict__ bv, f16* __restrict__ qs, f16* __restrict__ kp,
    f16* __restrict__ vpTg) {
  __shared__ __align__(16) char smem[40960];
  const int bid = blockIdx.x;
  if (bid < 128) {
    proj_body(q, WqT, bq, qs, 1024, 10, (bid & 15) * 128, (bid >> 4) * 128, smem);
  } else if (bid < 384) {
    int i = bid - 128;
    proj_body(k, WkT, bk, kp, 2048, 11, (i & 31) * 128, (i >> 5) * 128, smem);
  } else {
    vproj_body(v, WvT, bv, vpTg, (bid - 384) * 64, smem);
  }
}

// ---------------- fused attention -----------------------------------------
// grid 512: (pair 16) x (qt 16) x (head-half 2), XCD-swizzled.
// Swapped QK^T: lane owns one q row; round-8 store loop (1KB/wave-row).
__global__ __launch_bounds__(256, 2) void fused_attn_kernel(
    const f16* __restrict__ qs, const f16* __restrict__ kp,
    const f16* __restrict__ vpTg, float* __restrict__ attn_out,
    f16* __restrict__ mhp) {
  __shared__ __align__(16) char Kbuf[2][32768];

  const int bid = blockIdx.x;
  const int xcd = bid & 7, sub = bid >> 3;
  const int gg = xcd * 4 + (sub >> 4);  // 0..31
  const int qt = sub & 15;
  const int pair = gg & 15, hgIdx = gg >> 4;
  const int b = pair >> 3, n = pair & 7;
  const int q0 = qt * 64;

  const int tid = threadIdx.x, lane = tid & 63, w = tid >> 6;
  const int l15 = lane & 15, l4 = lane >> 4;

  // per-lane inverse-swizzled source offset (rule #21)
  const int laneoff =
      (lane >> 3) * 128 + (((lane & 7) * 16) ^ ((lane >> 3) << 4));

  // V fragments (wave's dv quarter), reused across all heads  [8 x b128]
  f16x8 vfrag[8];
  {
    const f16* vb = vpTg + ((size_t)(pair * 64 + w * 16 + l15)) * 256 + l4 * 8;
#pragma unroll
    for (int kc = 0; kc < 8; ++kc) vfrag[kc] = *(const f16x8*)(vb + kc * 32);
  }

#define STAGE_K(bufIdx, h)                                                      \
  {                                                                             \
    const char* src_ = (const char*)kp +                                        \
        ((size_t)((b * 16 + (h)) * 2048 + n * 256)) * 128;                      \
    char* lds_ = &Kbuf[bufIdx][0];                                              \
    _Pragma("unroll")                                                           \
    for (int j_ = 0; j_ < 8; ++j_) {                                            \
      int ch_ = w * 8 + j_;                                                     \
      __builtin_amdgcn_global_load_lds(                                         \
          (const __attribute__((address_space(1))) unsigned int*)(src_ +        \
              ch_ * 1024 + laneoff),                                            \
          (__attribute__((address_space(3))) unsigned int*)(lds_ + ch_ * 1024), \
          16, 0, 0);                                                            \
    }                                                                           \
  }

#define LOAD_Q(h, a0, a1)                                                       \
  {                                                                             \
    const f16* qp_ = qs +                                                       \
        ((size_t)((b * 16 + (h)) * 1024 + q0 + w * 16 + l15)) * 64 + l4 * 8;    \
    a0 = *(const f16x8*)qp_;                                                    \
    a1 = *(const f16x8*)(qp_ + 32);                                             \
  }

  f16x8 qa0, qa1, qn0, qn1;
  STAGE_K(0, hgIdx * 8);            // 8 loads
  LOAD_Q(hgIdx * 8, qa0, qa1);      // 2 loads
  qn0 = qa0; qn1 = qa1;

  f32x4 accO[4];
#pragma unroll
  for (int i = 0; i < 4; ++i) accO[i] = (f32x4)0.f;

  // outstanding: vfrag(8) + stage(8) + Q(2); vmcnt(2) => vfrag+stage retired
  asm volatile("s_waitcnt vmcnt(2)" ::: "memory");
  __builtin_amdgcn_s_barrier();

  const int ql = w * 16 + l15;        // this lane's q row within the 64-tile
  const int swq = (ql & 7) << 4;      // P swizzle for this lane's row

#pragma unroll 1
  for (int hh = 0; hh < 8; ++hh) {
    const int h = hgIdx * 8 + hh;
    const int cur = hh & 1;
    if (hh < 7) {
      STAGE_K(cur ^ 1, h + 1);      // 8 loads (oldest of this iteration)
      LOAD_Q(h + 1, qn0, qn1);      // 2 loads
    }

    // ---- QK^T (swapped): accS[sf][r] = S[q=ql][s=sf*16+l4*4+r] ----
    f32x4 accS[16];
#pragma unroll
    for (int sf = 0; sf < 16; ++sf) accS[sf] = (f32x4)0.f;
    const char* Kc = &Kbuf[cur][0];
    {
      const int sw = (l15 & 7) << 4;
      __builtin_amdgcn_s_setprio(1);
#pragma unroll
      for (int sf = 0; sf < 16; ++sf) {
        const int rowb = (sf * 16 + l15) * 128;
        f16x8 b0 = *(const f16x8*)(Kc + rowb + ((l4 * 16) ^ sw));
        f16x8 b1 = *(const f16x8*)(Kc + rowb + ((64 + l4 * 16) ^ sw));
        accS[sf] = MFMA_F16(b0, qa0, accS[sf]);
        accS[sf] = MFMA_F16(b1, qa1, accS[sf]);
      }
      __builtin_amdgcn_s_setprio(0);
    }

    // ---- softmax: lane-local row, 2+2 shfl across l4 groups ----
    float mx = -3.0e38f;
    if (q0 < SEGW) {  // uniform: only qt<4 ever masks
      const int qg = q0 + ql;
#pragma unroll
      for (int sf = 0; sf < 16; ++sf)
#pragma unroll
        for (int r = 0; r < 4; ++r) {
          int s = sf * 16 + l4 * 4 + r;
          float vv = accS[sf][r] * 0.125f;
          if (s > qg) vv = -3.0e38f;
          accS[sf][r] = vv;
          mx = fmaxf(mx, vv);
        }
    } else {
#pragma unroll
      for (int sf = 0; sf < 16; ++sf)
#pragma unroll
        for (int r = 0; r < 4; ++r) {
          float vv = accS[sf][r] * 0.125f;
          accS[sf][r] = vv;
          mx = fmaxf(mx, vv);
        }
    }
    mx = fmaxf(mx, __shfl_xor(mx, 16));
    mx = fmaxf(mx, __shfl_xor(mx, 32));
    float sum = 0.f;
#pragma unroll
    for (int sf = 0; sf < 16; ++sf)
#pragma unroll
      for (int r = 0; r < 4; ++r) {
        float e = __expf(accS[sf][r] - mx);
        accS[sf][r] = e;
        sum += e;
      }
    sum += __shfl_xor(sum, 16);
    sum += __shfl_xor(sum, 32);
    const float inv = 1.0f / sum;

    // all waves done reading K[cur] -> safe to overlay P
    asm volatile("s_waitcnt lgkmcnt(0)" ::: "memory");
    __builtin_amdgcn_s_barrier();

    // ---- write P (f16, swizzled): 16 x ds_write_b64, 4 consecutive s ----
    char* Pc = &Kbuf[cur][0];
#pragma unroll
    for (int sf = 0; sf < 16; ++sf) {
      f16x4 p4;
      p4[0] = (f16)(accS[sf][0] * inv);
      p4[1] = (f16)(accS[sf][1] * inv);
      p4[2] = (f16)(accS[sf][2] * inv);
      p4[3] = (f16)(accS[sf][3] * inv);
      *(f16x4*)(Pc + ql * 512 + ((sf * 32 + l4 * 8) ^ swq)) = p4;
    }
    asm volatile("s_waitcnt lgkmcnt(0)" ::: "memory");
    __builtin_amdgcn_s_barrier();

    // ---- PV first: MFMAs enter the pipe; stores issue under them ----
    __builtin_amdgcn_s_setprio(1);
#pragma unroll
    for (int kc = 0; kc < 8; ++kc) {
#pragma unroll
      for (int qb = 0; qb < 4; ++qb) {
        const int qr = qb * 16 + l15;
        f16x8 pa = *(const f16x8*)(Pc + qr * 512 +
                                   ((kc * 64 + l4 * 16) ^ ((qr & 7) << 4)));
        accO[qb] = MFMA_F16(pa, vfrag[kc], accO[qb]);
      }
    }
    __builtin_amdgcn_s_setprio(0);

    // ---- attn_out: contiguous 1KB per wave-row, NT stores (16 / lane) ----
    {
      const size_t base0 =
          (((size_t)b * LTOT + (size_t)n * LQ + q0) * H_ + h) * SEGW;
#pragma unroll
      for (int it = 0; it < 16; ++it) {
        const int qr = w * 16 + it;
        f16x4 p4 =
            *(const f16x4*)(Pc + qr * 512 + ((lane * 8) ^ ((qr & 7) << 4)));
        f32x4 f;
        f[0] = (float)p4[0]; f[1] = (float)p4[1];
        f[2] = (float)p4[2]; f[3] = (float)p4[3];
        __builtin_nontemporal_store(
            f, (f32x4*)(attn_out + base0 + (size_t)qr * (H_ * SEGW) + lane * 4));
      }
    }

    qa0 = qn0; qa1 = qn1;
    // vmcnt(16): drains stage+Q, leaves this head's 16 NT stores draining
    // under head h+1's compute.
    asm volatile("s_waitcnt lgkmcnt(0)" ::: "memory");
    asm volatile("s_waitcnt vmcnt(16)" ::: "memory");
    __builtin_amdgcn_s_barrier();
  }

  // ---- epilogue: coalesced mhp via LDS repack (Kbuf[0] dead) ----
  {
    f16(*Lst)[64] = (f16(*)[64]) & Kbuf[0][0];  // 64 q x 64 dv = 8 KB
    const float s16 = 1.0f / 16.0f;
#pragma unroll
    for (int qb = 0; qb < 4; ++qb)
#pragma unroll
      for (int r = 0; r < 4; ++r)
        Lst[qb * 16 + l4 * 4 + r][w * 16 + l15] = (f16)(accO[qb][r] * s16);
    __syncthreads();
    f16* mp = mhp + ((size_t)hgIdx * 16384 + (size_t)pair * 1024 + q0) * 64;
    const int row = tid >> 2, col = (tid & 3) * 16;
    f16x8 v0 = *(const f16x8*)&Lst[row][col];
    f16x8 v1 = *(const f16x8*)&Lst[row][col + 8];
    *(f16x8*)(mp + (size_t)row * 64 + col) = v0;
    *(f16x8*)(mp + (size_t)row * 64 + col + 8) = v1;
  }
#undef STAGE_K
#undef LOAD_Q
}

// ---------------- final: outputs = (mhp0+mhp1)[16384,64] @ Wh[64,1024] -----
__global__ __launch_bounds__(256) void final_f16_kernel(
    const f16* __restrict__ mhp, const f16* __restrict__ WhT,
    float* __restrict__ outputs) {
  __shared__ __align__(16) char smemF[33792];
  f16(*Af)[72] = (f16(*)[72])smemF;
  f16(*Bf)[72] = (f16(*)[72])(smemF + 9216);
  const int m0 = blockIdx.x * 64, c0 = blockIdx.y * 128;
  const int tid = threadIdx.x, lane = tid & 63, w = tid >> 6;
  const int l15 = lane & 15, l4 = lane >> 4;
  {
    int u = tid & 7, row0 = tid >> 3;
#pragma unroll
    for (int p = 0; p < 2; ++p) {
      int r = row0 + p * 32;
      size_t mi = (size_t)(m0 + r) * 64 + u * 8;
      f16x8 a0 = *(const f16x8*)(mhp + mi);
      f16x8 a1 = *(const f16x8*)(mhp + (size_t)16384 * 64 + mi);
      *(f16x8*)&Af[r][u * 8] = a0 + a1;
    }
    int cb = tid >> 3;
#pragma unroll
    for (int p = 0; p < 4; ++p) {
      int c = cb + p * 32;
      *(f16x8*)&Bf[c][u * 8] = *(const f16x8*)(WhT + (size_t)(c0 + c) * 64 + u * 8);
    }
  }
  __syncthreads();

  f32x4 acc[8];
#pragma unroll
  for (int cf = 0; cf < 8; ++cf) acc[cf] = (f32x4)0.f;
#pragma unroll
  for (int kc = 0; kc < 2; ++kc) {
    f16x8 a8 = *(const f16x8*)&Af[w * 16 + l15][kc * 32 + l4 * 8];
#pragma unroll
    for (int cf = 0; cf < 8; ++cf) {
      f16x8 b8 = *(const f16x8*)&Bf[cf * 16 + l15][kc * 32 + l4 * 8];
      acc[cf] = MFMA_F16(a8, b8, acc[cf]);
    }
  }
  __syncthreads();  // Af/Bf reads done -> overlay staging

  // ---- coalesced outputs store via LDS repack ----
  float(*Cst)[132] = (float(*)[132])smemF;
#pragma unroll
  for (int cf = 0; cf < 8; ++cf)
#pragma unroll
    for (int r = 0; r < 4; ++r)
      Cst[w * 16 + l4 * 4 + r][cf * 16 + l15] = acc[cf][r];
  __syncthreads();
#pragma unroll
  for (int p = 0; p < 8; ++p) {
    int row = p * 8 + (tid >> 5);
    int col = (tid & 31) * 4;
    f32x4 vv = *(const f32x4*)&Cst[row][col];
    __builtin_nontemporal_store(
        vv, (f32x4*)(outputs + (size_t)(m0 + row) * 1024 + c0 + col));
  }
}

// ---------------------------------------------------------------------------
extern "C" void kernel_launch(void* const* d_in, const int* in_sizes, int n_in,
                              void* d_out, int out_size, void* d_ws,
                              size_t ws_size, hipStream_t stream) {
  const float* q  = (const float*)d_in[0];
  const float* k  = (const float*)d_in[1];
  const float* v  = (const float*)d_in[2];
  const float* Wq = (const float*)d_in[3];
  const float* bq = (const float*)d_in[4];
  const float* Wk = (const float*)d_in[5];
  const float* bk = (const float*)d_in[6];
  const float* Wv = (const float*)d_in[7];
  const float* bv = (const float*)d_in[8];
  const float* Wh = (const float*)d_in[9];

  float* outputs  = (float*)d_out;
  float* attn_out = (float*)d_out + (size_t)B_ * LTOT * D_;

  char* ws = (char*)d_ws;
  f16* WqT  = (f16*)(ws + 0);                       // 2MB
  f16* WkT  = (f16*)(ws + (2u << 20));              // 2MB
  f16* WvT  = (f16*)(ws + (4u << 20));              // 128KB
  f16* WhT  = (f16*)(ws + (4u << 20) + 131072);     // 128KB
  f16* qs   = (f16*)(ws + (4u << 20) + 262144);     // 4MB
  f16* kp   = (f16*)((char*)qs + (4u << 20));       // 8MB
  f16* vpTg = (f16*)((char*)kp + (8u << 20));       // 512KB
  f16* mhp  = (f16*)((char*)vpTg + (1u << 19));     // 4MB (2 partials)

  prep_kernel<<<dim3(544), 256, 0, stream>>>(Wq, Wk, Wv, Wh, WqT, WkT, WvT, WhT);
  proj_all_kernel<<<dim3(448), 256, 0, stream>>>(q, k, v, WqT, WkT, WvT, bq, bk,
                                                 bv, qs, kp, vpTg);
  fused_attn_kernel<<<dim3(512), 256, 0, stream>>>(qs, kp, vpTg, attn_out, mhp);
  final_f16_kernel<<<dim3(256, 8), 256, 0, stream>>>(mhp, WhT, outputs);
}